// Round 1
// baseline (64.568 us; speedup 1.0000x reference)
//
#include <hip/hip_runtime.h>
#include <math.h>

constexpr int BATCH_N = 16384;
constexpr float INV_B = 1.0f / 16384.0f;
constexpr float BN_EPS_C = 1e-5f;
constexpr int NUM_USERS_C = 1000000;

// ---------------------------------------------------------------------------
// K1: gather X(B,128) from tables, GEMM vs W1^T(128->256), +b1, ReLU -> h1
//     plus per-column sum / sumsq partials (atomicAdd once per block/column).
// Tile: BM=64 rows, BN=128 cols (cb in {0,1}), BK=64 (kt in {0,1}).
// Threads 256: tx=col-group (8 cols: 4tx..4tx+3 and 64+4tx..), ty=row-group (4 rows).
// ---------------------------------------------------------------------------
__global__ __launch_bounds__(256, 2) void wd_k1(
    const int* __restrict__ ui, const int* __restrict__ ii,
    const float* __restrict__ utab, const float* __restrict__ itab,
    const float* __restrict__ W1, const float* __restrict__ b1,
    float* __restrict__ h1, float* __restrict__ sum1, float* __restrict__ sumsq1)
{
    __shared__ float xs[64 * 68];     // X tile, row-major, pitch 68 (17.4 KB)
    __shared__ float wsm[64 * 128];   // W tile, k-major [k][j]   (32 KB)
    __shared__ int us[64], is_[64];

    const int tid = threadIdx.x;
    const int cb = blockIdx.x;        // 0..1  -> output cols cb*128..+127
    const int rb = blockIdx.y;        // 0..255 -> rows rb*64..+63
    const int row0 = rb * 64;
    const int col0 = cb * 128;

    if (tid < 64) us[tid] = ui[row0 + tid];
    else if (tid < 128) is_[tid - 64] = ii[row0 + tid - 64];
    __syncthreads();

    const int tx = tid & 15, ty = tid >> 4;
    float acc[4][8];
#pragma unroll
    for (int r = 0; r < 4; ++r)
#pragma unroll
        for (int c = 0; c < 8; ++c) acc[r][c] = 0.f;

    for (int kt = 0; kt < 2; ++kt) {
        if (kt) __syncthreads();
        // stage X: kt==0 -> user embedding cols, kt==1 -> item embedding cols
#pragma unroll
        for (int itr = 0; itr < 4; ++itr) {
            int idx = itr * 256 + tid;
            int r = idx >> 4, c4 = idx & 15;
            const float* src = (kt == 0)
                ? (utab + (size_t)us[r] * 64 + c4 * 4)
                : (itab + (size_t)is_[r] * 64 + c4 * 4);
            float4 v = *(const float4*)src;
            *(float4*)&xs[r * 68 + c4 * 4] = v;
        }
        // stage W (transpose to k-major; LDS writes contiguous in j -> conflict-free)
#pragma unroll
        for (int itr = 0; itr < 8; ++itr) {
            int idx = itr * 256 + tid;
            int j = idx & 127, k4 = idx >> 7;   // k4: 0..15
            float4 g = *(const float4*)&W1[(size_t)(col0 + j) * 128 + kt * 64 + k4 * 4];
            wsm[(k4 * 4 + 0) * 128 + j] = g.x;
            wsm[(k4 * 4 + 1) * 128 + j] = g.y;
            wsm[(k4 * 4 + 2) * 128 + j] = g.z;
            wsm[(k4 * 4 + 3) * 128 + j] = g.w;
        }
        __syncthreads();
        // compute
        for (int k4 = 0; k4 < 16; ++k4) {
            float xk[4][4];
#pragma unroll
            for (int r = 0; r < 4; ++r) {
                float4 t = *(const float4*)&xs[(ty * 4 + r) * 68 + k4 * 4];
                xk[r][0] = t.x; xk[r][1] = t.y; xk[r][2] = t.z; xk[r][3] = t.w;
            }
#pragma unroll
            for (int kk = 0; kk < 4; ++kk) {
                float4 wa = *(const float4*)&wsm[(k4 * 4 + kk) * 128 + tx * 4];
                float4 wb = *(const float4*)&wsm[(k4 * 4 + kk) * 128 + 64 + tx * 4];
#pragma unroll
                for (int r = 0; r < 4; ++r) {
                    float x = xk[r][kk];
                    acc[r][0] = fmaf(x, wa.x, acc[r][0]);
                    acc[r][1] = fmaf(x, wa.y, acc[r][1]);
                    acc[r][2] = fmaf(x, wa.z, acc[r][2]);
                    acc[r][3] = fmaf(x, wa.w, acc[r][3]);
                    acc[r][4] = fmaf(x, wb.x, acc[r][4]);
                    acc[r][5] = fmaf(x, wb.y, acc[r][5]);
                    acc[r][6] = fmaf(x, wb.z, acc[r][6]);
                    acc[r][7] = fmaf(x, wb.w, acc[r][7]);
                }
            }
        }
    }

    // epilogue: bias + relu + store + column partial sums
    float ba[4], bb[4];
#pragma unroll
    for (int c = 0; c < 4; ++c) {
        ba[c] = b1[col0 + tx * 4 + c];
        bb[c] = b1[col0 + 64 + tx * 4 + c];
    }
    float sums[8], sqs[8];
#pragma unroll
    for (int c = 0; c < 8; ++c) { sums[c] = 0.f; sqs[c] = 0.f; }
#pragma unroll
    for (int r = 0; r < 4; ++r) {
        int row = row0 + ty * 4 + r;
        float4 oa, ob;
        oa.x = fmaxf(acc[r][0] + ba[0], 0.f);
        oa.y = fmaxf(acc[r][1] + ba[1], 0.f);
        oa.z = fmaxf(acc[r][2] + ba[2], 0.f);
        oa.w = fmaxf(acc[r][3] + ba[3], 0.f);
        ob.x = fmaxf(acc[r][4] + bb[0], 0.f);
        ob.y = fmaxf(acc[r][5] + bb[1], 0.f);
        ob.z = fmaxf(acc[r][6] + bb[2], 0.f);
        ob.w = fmaxf(acc[r][7] + bb[3], 0.f);
        *(float4*)&h1[(size_t)row * 256 + col0 + tx * 4] = oa;
        *(float4*)&h1[(size_t)row * 256 + col0 + 64 + tx * 4] = ob;
        sums[0] += oa.x; sqs[0] += oa.x * oa.x;
        sums[1] += oa.y; sqs[1] += oa.y * oa.y;
        sums[2] += oa.z; sqs[2] += oa.z * oa.z;
        sums[3] += oa.w; sqs[3] += oa.w * oa.w;
        sums[4] += ob.x; sqs[4] += ob.x * ob.x;
        sums[5] += ob.y; sqs[5] += ob.y * ob.y;
        sums[6] += ob.z; sqs[6] += ob.z * ob.z;
        sums[7] += ob.w; sqs[7] += ob.w * ob.w;
    }
    __syncthreads();                 // done reading xs; reuse as reduction scratch
    float* red_s = xs;               // [16][128]
    float* red_q = xs + 2048;        // [16][128]
#pragma unroll
    for (int c = 0; c < 4; ++c) {
        red_s[ty * 128 + tx * 4 + c] = sums[c];
        red_s[ty * 128 + 64 + tx * 4 + c] = sums[4 + c];
        red_q[ty * 128 + tx * 4 + c] = sqs[c];
        red_q[ty * 128 + 64 + tx * 4 + c] = sqs[4 + c];
    }
    __syncthreads();
    if (tid < 128) {
        float s = 0.f;
#pragma unroll
        for (int t = 0; t < 16; ++t) s += red_s[t * 128 + tid];
        atomicAdd(&sum1[col0 + tid], s);
    } else {
        int c = tid - 128;
        float q = 0.f;
#pragma unroll
        for (int t = 0; t < 16; ++t) q += red_q[t * 128 + c];
        atomicAdd(&sumsq1[col0 + c], q);
    }
}

// ---------------------------------------------------------------------------
// K2: BN1(affine from sums) applied on the fly to h1, GEMM vs W2^T(256->128),
//     +b2, ReLU -> h2, plus column sum/sumsq partials for BN2.
// Tile: BM=64, BN=128 (all cols), BK=64 (kt 0..3).
// ---------------------------------------------------------------------------
__global__ __launch_bounds__(256, 2) void wd_k2(
    const float* __restrict__ h1,
    const float* __restrict__ sum1, const float* __restrict__ sumsq1,
    const float* __restrict__ g1, const float* __restrict__ be1,
    const float* __restrict__ W2, const float* __restrict__ b2,
    float* __restrict__ h2, float* __restrict__ sum2, float* __restrict__ sumsq2)
{
    __shared__ float xs[64 * 68];
    __shared__ float wsm[64 * 128];
    __shared__ float a1s[256], c1s[256];

    const int tid = threadIdx.x;
    const int rb = blockIdx.x;
    const int row0 = rb * 64;

    {   // BN1 affine: h1n = a*h1 + c
        float s = sum1[tid], q = sumsq1[tid];
        float mu = s * INV_B;
        float var = fmaf(q, INV_B, -mu * mu);
        float rs = rsqrtf(var + BN_EPS_C);
        float a = g1[tid] * rs;
        a1s[tid] = a;
        c1s[tid] = fmaf(-mu, a, be1[tid]);
    }
    __syncthreads();

    const int tx = tid & 15, ty = tid >> 4;
    float acc[4][8];
#pragma unroll
    for (int r = 0; r < 4; ++r)
#pragma unroll
        for (int c = 0; c < 8; ++c) acc[r][c] = 0.f;

    for (int kt = 0; kt < 4; ++kt) {
        if (kt) __syncthreads();
        // stage X tile with BN affine applied
#pragma unroll
        for (int itr = 0; itr < 4; ++itr) {
            int idx = itr * 256 + tid;
            int r = idx >> 4, c4 = idx & 15;
            int k = kt * 64 + c4 * 4;
            float4 v = *(const float4*)&h1[(size_t)(row0 + r) * 256 + k];
            v.x = fmaf(a1s[k + 0], v.x, c1s[k + 0]);
            v.y = fmaf(a1s[k + 1], v.y, c1s[k + 1]);
            v.z = fmaf(a1s[k + 2], v.z, c1s[k + 2]);
            v.w = fmaf(a1s[k + 3], v.w, c1s[k + 3]);
            *(float4*)&xs[r * 68 + c4 * 4] = v;
        }
        // stage W2 tile (k-major)
#pragma unroll
        for (int itr = 0; itr < 8; ++itr) {
            int idx = itr * 256 + tid;
            int j = idx & 127, k4 = idx >> 7;
            float4 g = *(const float4*)&W2[(size_t)j * 256 + kt * 64 + k4 * 4];
            wsm[(k4 * 4 + 0) * 128 + j] = g.x;
            wsm[(k4 * 4 + 1) * 128 + j] = g.y;
            wsm[(k4 * 4 + 2) * 128 + j] = g.z;
            wsm[(k4 * 4 + 3) * 128 + j] = g.w;
        }
        __syncthreads();
        for (int k4 = 0; k4 < 16; ++k4) {
            float xk[4][4];
#pragma unroll
            for (int r = 0; r < 4; ++r) {
                float4 t = *(const float4*)&xs[(ty * 4 + r) * 68 + k4 * 4];
                xk[r][0] = t.x; xk[r][1] = t.y; xk[r][2] = t.z; xk[r][3] = t.w;
            }
#pragma unroll
            for (int kk = 0; kk < 4; ++kk) {
                float4 wa = *(const float4*)&wsm[(k4 * 4 + kk) * 128 + tx * 4];
                float4 wb = *(const float4*)&wsm[(k4 * 4 + kk) * 128 + 64 + tx * 4];
#pragma unroll
                for (int r = 0; r < 4; ++r) {
                    float x = xk[r][kk];
                    acc[r][0] = fmaf(x, wa.x, acc[r][0]);
                    acc[r][1] = fmaf(x, wa.y, acc[r][1]);
                    acc[r][2] = fmaf(x, wa.z, acc[r][2]);
                    acc[r][3] = fmaf(x, wa.w, acc[r][3]);
                    acc[r][4] = fmaf(x, wb.x, acc[r][4]);
                    acc[r][5] = fmaf(x, wb.y, acc[r][5]);
                    acc[r][6] = fmaf(x, wb.z, acc[r][6]);
                    acc[r][7] = fmaf(x, wb.w, acc[r][7]);
                }
            }
        }
    }

    float ba[4], bb[4];
#pragma unroll
    for (int c = 0; c < 4; ++c) {
        ba[c] = b2[tx * 4 + c];
        bb[c] = b2[64 + tx * 4 + c];
    }
    float sums[8], sqs[8];
#pragma unroll
    for (int c = 0; c < 8; ++c) { sums[c] = 0.f; sqs[c] = 0.f; }
#pragma unroll
    for (int r = 0; r < 4; ++r) {
        int row = row0 + ty * 4 + r;
        float4 oa, ob;
        oa.x = fmaxf(acc[r][0] + ba[0], 0.f);
        oa.y = fmaxf(acc[r][1] + ba[1], 0.f);
        oa.z = fmaxf(acc[r][2] + ba[2], 0.f);
        oa.w = fmaxf(acc[r][3] + ba[3], 0.f);
        ob.x = fmaxf(acc[r][4] + bb[0], 0.f);
        ob.y = fmaxf(acc[r][5] + bb[1], 0.f);
        ob.z = fmaxf(acc[r][6] + bb[2], 0.f);
        ob.w = fmaxf(acc[r][7] + bb[3], 0.f);
        *(float4*)&h2[(size_t)row * 128 + tx * 4] = oa;
        *(float4*)&h2[(size_t)row * 128 + 64 + tx * 4] = ob;
        sums[0] += oa.x; sqs[0] += oa.x * oa.x;
        sums[1] += oa.y; sqs[1] += oa.y * oa.y;
        sums[2] += oa.z; sqs[2] += oa.z * oa.z;
        sums[3] += oa.w; sqs[3] += oa.w * oa.w;
        sums[4] += ob.x; sqs[4] += ob.x * ob.x;
        sums[5] += ob.y; sqs[5] += ob.y * ob.y;
        sums[6] += ob.z; sqs[6] += ob.z * ob.z;
        sums[7] += ob.w; sqs[7] += ob.w * ob.w;
    }
    __syncthreads();
    float* red_s = xs;
    float* red_q = xs + 2048;
#pragma unroll
    for (int c = 0; c < 4; ++c) {
        red_s[ty * 128 + tx * 4 + c] = sums[c];
        red_s[ty * 128 + 64 + tx * 4 + c] = sums[4 + c];
        red_q[ty * 128 + tx * 4 + c] = sqs[c];
        red_q[ty * 128 + 64 + tx * 4 + c] = sqs[4 + c];
    }
    __syncthreads();
    if (tid < 128) {
        float s = 0.f;
#pragma unroll
        for (int t = 0; t < 16; ++t) s += red_s[t * 128 + tid];
        atomicAdd(&sum2[tid], s);
    } else {
        int c = tid - 128;
        float q = 0.f;
#pragma unroll
        for (int t = 0; t < 16; ++t) q += red_q[t * 128 + c];
        atomicAdd(&sumsq2[c], q);
    }
}

// ---------------------------------------------------------------------------
// K3: BN2 folded into per-feature (a2*W3, c2*W3); deep dot (4 lanes/row),
//     + wide gather + biases, sigmoid -> out.  64 rows per block.
// ---------------------------------------------------------------------------
__global__ __launch_bounds__(256) void wd_k3(
    const int* __restrict__ ui, const int* __restrict__ ii,
    const float* __restrict__ wide_w, const float* __restrict__ wide_b,
    const float* __restrict__ h2,
    const float* __restrict__ sum2, const float* __restrict__ sumsq2,
    const float* __restrict__ g2, const float* __restrict__ be2,
    const float* __restrict__ W3, const float* __restrict__ b3,
    float* __restrict__ out)
{
    __shared__ float af[128], cf[128];
    const int tid = threadIdx.x;
    if (tid < 128) {
        float s = sum2[tid], q = sumsq2[tid];
        float mu = s * INV_B;
        float var = fmaf(q, INV_B, -mu * mu);
        float rs = rsqrtf(var + BN_EPS_C);
        float a = g2[tid] * rs;
        float c = fmaf(-mu, a, be2[tid]);
        float w = W3[tid];
        af[tid] = a * w;
        cf[tid] = c * w;
    }
    __syncthreads();

    const int row = blockIdx.x * 64 + (tid >> 2);
    const int kq = tid & 3;
    const float* hrow = h2 + (size_t)row * 128 + kq * 32;
    const float* afp = af + kq * 32;
    const float* cfp = cf + kq * 32;
    float acc = 0.f;
#pragma unroll
    for (int j = 0; j < 8; ++j) {
        float4 h = *(const float4*)&hrow[j * 4];
        float4 a4 = *(const float4*)&afp[j * 4];
        float4 c4 = *(const float4*)&cfp[j * 4];
        acc += fmaf(h.x, a4.x, c4.x);
        acc += fmaf(h.y, a4.y, c4.y);
        acc += fmaf(h.z, a4.z, c4.z);
        acc += fmaf(h.w, a4.w, c4.w);
    }
    acc += __shfl_xor(acc, 1);
    acc += __shfl_xor(acc, 2);
    if (kq == 0) {
        int u = ui[row], iv = ii[row];
        float wide = wide_w[u] + wide_w[NUM_USERS_C + iv] + wide_b[0];
        float logit = acc + b3[0] + wide;
        out[row] = 1.f / (1.f + expf(-logit));
    }
}

extern "C" void kernel_launch(void* const* d_in, const int* in_sizes, int n_in,
                              void* d_out, int out_size, void* d_ws, size_t ws_size,
                              hipStream_t stream)
{
    const int*   ui     = (const int*)d_in[0];
    const int*   ii     = (const int*)d_in[1];
    const float* wide_w = (const float*)d_in[2];
    const float* wide_b = (const float*)d_in[3];
    const float* utab   = (const float*)d_in[4];
    const float* itab   = (const float*)d_in[5];
    const float* W1     = (const float*)d_in[6];
    const float* b1     = (const float*)d_in[7];
    const float* g1     = (const float*)d_in[8];
    const float* be1    = (const float*)d_in[9];
    const float* W2     = (const float*)d_in[10];
    const float* b2     = (const float*)d_in[11];
    const float* g2     = (const float*)d_in[12];
    const float* be2    = (const float*)d_in[13];
    const float* W3     = (const float*)d_in[14];
    const float* b3     = (const float*)d_in[15];
    float* out = (float*)d_out;

    float* ws = (float*)d_ws;
    float* h1 = ws;                                   // 16384*256
    float* h2 = ws + (size_t)16384 * 256;             // 16384*128
    float* stats = h2 + (size_t)16384 * 128;          // 768 floats
    float* sum1 = stats;
    float* sumsq1 = stats + 256;
    float* sum2 = stats + 512;
    float* sumsq2 = stats + 640;

    hipMemsetAsync(stats, 0, 768 * sizeof(float), stream);

    wd_k1<<<dim3(2, 256), 256, 0, stream>>>(ui, ii, utab, itab, W1, b1, h1, sum1, sumsq1);
    wd_k2<<<256, 256, 0, stream>>>(h1, sum1, sumsq1, g1, be1, W2, b2, h2, sum2, sumsq2);
    wd_k3<<<256, 256, 0, stream>>>(ui, ii, wide_w, wide_b, h2, sum2, sumsq2, g2, be2, W3, b3, out);
}

// Round 2
// 44.492 us; speedup vs baseline: 1.4512x; 1.4512x over previous
//
#include <hip/hip_runtime.h>
#include <math.h>

constexpr float INV_B = 1.0f / 16384.0f;
constexpr float BN_EPS_C = 1e-5f;
constexpr int NUM_USERS_C = 1000000;

typedef __attribute__((ext_vector_type(8))) short bf16x8;
typedef __attribute__((ext_vector_type(4))) float f32x4;

__device__ inline unsigned short f2bf(float f) {
    union { float f; unsigned u; } v; v.f = f;
    unsigned r = v.u + 0x7FFFu + ((v.u >> 16) & 1u);   // RNE
    return (unsigned short)(r >> 16);
}
__device__ inline float bf2f(unsigned short h) {
    union { unsigned u; float f; } v; v.u = ((unsigned)h) << 16; return v.f;
}
// byte offset into a [rows][128 bf16] tile (256B pitch), bank-conflict swizzle
__device__ inline unsigned swz(int row, int kbyte) {
    return (unsigned)(row * 256 + (kbyte ^ ((row & 7) << 4)));
}

// ---------------------------------------------------------------------------
// K1: gather X(bf16) from tables, MFMA GEMM vs W1^T(128->256), +b1, ReLU
//     -> h1 (bf16), plus per-column sum/sumsq (fp32) via atomics.
// Grid (2,128): cb = N-half (128 cols), rb = 128-row tile. 256 thr = 4 waves.
// ---------------------------------------------------------------------------
__global__ __launch_bounds__(256, 2) void wd_k1(
    const int* __restrict__ ui, const int* __restrict__ ii,
    const float* __restrict__ utab, const float* __restrict__ itab,
    const float* __restrict__ W1, const float* __restrict__ b1,
    unsigned short* __restrict__ h1, float* __restrict__ sum1, float* __restrict__ sumsq1)
{
    __shared__ unsigned short Xs[128 * 128];   // 32 KB, swizzled [row][k]
    __shared__ unsigned short Wsm[128 * 128];  // 32 KB, swizzled [n][k]

    const int tid = threadIdx.x;
    const int cb = blockIdx.x;
    const int rb = blockIdx.y;
    const int row0 = rb * 128;
    const int col0 = cb * 128;

    // ---- stage X (gather + fp32->bf16) ----
#pragma unroll
    for (int iter = 0; iter < 8; ++iter) {
        int idx = iter * 256 + tid;
        int row = idx >> 4, chunk = idx & 15;
        int gr = row0 + row;
        const float* src;
        if (chunk < 8) { int u = ui[gr];  src = utab + (size_t)u * 64 + chunk * 8; }
        else           { int it = ii[gr]; src = itab + (size_t)it * 64 + (chunk - 8) * 8; }
        float4 va = ((const float4*)src)[0];
        float4 vb = ((const float4*)src)[1];
        bf16x8 sv;
        sv[0] = (short)f2bf(va.x); sv[1] = (short)f2bf(va.y);
        sv[2] = (short)f2bf(va.z); sv[3] = (short)f2bf(va.w);
        sv[4] = (short)f2bf(vb.x); sv[5] = (short)f2bf(vb.y);
        sv[6] = (short)f2bf(vb.z); sv[7] = (short)f2bf(vb.w);
        *(bf16x8*)((char*)Xs + swz(row, chunk * 16)) = sv;
    }
    // ---- stage W1 half ----
#pragma unroll
    for (int iter = 0; iter < 8; ++iter) {
        int idx = iter * 256 + tid;
        int n = idx >> 4, chunk = idx & 15;
        const float* src = W1 + (size_t)(col0 + n) * 128 + chunk * 8;
        float4 va = ((const float4*)src)[0];
        float4 vb = ((const float4*)src)[1];
        bf16x8 sv;
        sv[0] = (short)f2bf(va.x); sv[1] = (short)f2bf(va.y);
        sv[2] = (short)f2bf(va.z); sv[3] = (short)f2bf(va.w);
        sv[4] = (short)f2bf(vb.x); sv[5] = (short)f2bf(vb.y);
        sv[6] = (short)f2bf(vb.z); sv[7] = (short)f2bf(vb.w);
        *(bf16x8*)((char*)Wsm + swz(n, chunk * 16)) = sv;
    }
    __syncthreads();

    // ---- MFMA: wave (wm,wn) owns 64x64; 4x4 frags of 16x16, K=128 in 4 steps
    const int w = tid >> 6, lane = tid & 63;
    const int wm = w >> 1, wn = w & 1;
    const int lr = lane & 15, lk = lane >> 4;
    f32x4 acc[4][4];
#pragma unroll
    for (int i = 0; i < 4; ++i)
#pragma unroll
        for (int j = 0; j < 4; ++j) acc[i][j] = (f32x4){0.f, 0.f, 0.f, 0.f};

#pragma unroll
    for (int kst = 0; kst < 4; ++kst) {
        int kbyte = kst * 64 + lk * 16;
        bf16x8 a[4], b[4];
#pragma unroll
        for (int mi = 0; mi < 4; ++mi)
            a[mi] = *(const bf16x8*)((const char*)Xs + swz(wm * 64 + mi * 16 + lr, kbyte));
#pragma unroll
        for (int nj = 0; nj < 4; ++nj)
            b[nj] = *(const bf16x8*)((const char*)Wsm + swz(wn * 64 + nj * 16 + lr, kbyte));
#pragma unroll
        for (int mi = 0; mi < 4; ++mi)
#pragma unroll
            for (int nj = 0; nj < 4; ++nj)
                acc[mi][nj] = __builtin_amdgcn_mfma_f32_16x16x32_bf16(a[mi], b[nj], acc[mi][nj], 0, 0, 0);
    }

    __syncthreads();   // all LDS reads done; reuse Xs for output bounce, Wsm for stats

    float* ssum = (float*)Wsm;          // [128]
    float* ssq  = ssum + 128;           // [128]
    if (tid < 128) { ssum[tid] = 0.f; ssq[tid] = 0.f; }

    float bias[4];
#pragma unroll
    for (int nj = 0; nj < 4; ++nj) bias[nj] = b1[col0 + wn * 64 + nj * 16 + lr];

    float sums[4] = {0.f, 0.f, 0.f, 0.f}, sqs[4] = {0.f, 0.f, 0.f, 0.f};
#pragma unroll
    for (int mi = 0; mi < 4; ++mi)
#pragma unroll
        for (int nj = 0; nj < 4; ++nj)
#pragma unroll
            for (int reg = 0; reg < 4; ++reg) {
                int lrow = wm * 64 + mi * 16 + lk * 4 + reg;
                int lcol = wn * 64 + nj * 16 + lr;
                float v = fmaxf(acc[mi][nj][reg] + bias[nj], 0.f);
                unsigned short hb = f2bf(v);
                float vr = bf2f(hb);
                sums[nj] += vr; sqs[nj] += vr * vr;
                *(unsigned short*)((char*)Xs + swz(lrow, lcol * 2)) = hb;
            }
    __syncthreads();

    // coalesced bf16 store of the 128x128 tile + stats reduction
#pragma unroll
    for (int iter = 0; iter < 8; ++iter) {
        int idx = iter * 256 + tid;
        int row = idx >> 4, chunk = idx & 15;
        bf16x8 v = *(const bf16x8*)((const char*)Xs + swz(row, chunk * 16));
        *(bf16x8*)(h1 + (size_t)(row0 + row) * 256 + col0 + chunk * 8) = v;
    }
#pragma unroll
    for (int nj = 0; nj < 4; ++nj) {
        float s = sums[nj], q = sqs[nj];
        s += __shfl_xor(s, 16); s += __shfl_xor(s, 32);
        q += __shfl_xor(q, 16); q += __shfl_xor(q, 32);
        if (lane < 16) {
            atomicAdd(&ssum[wn * 64 + nj * 16 + lane], s);
            atomicAdd(&ssq[wn * 64 + nj * 16 + lane], q);
        }
    }
    __syncthreads();
    if (tid < 128) {
        atomicAdd(&sum1[col0 + tid], ssum[tid]);
        atomicAdd(&sumsq1[col0 + tid], ssq[tid]);
    }
}

// ---------------------------------------------------------------------------
// K2: BN1 affine folded into bf16 staging of h1; MFMA GEMM vs W2^T(256->128),
//     +b2, ReLU -> h2 (fp32), plus column sum/sumsq for BN2.
// Grid 256: rb = 64-row tile. 4 waves: wave = 32 rows x 64 cols. BK=128 x2.
// ---------------------------------------------------------------------------
__global__ __launch_bounds__(256, 2) void wd_k2(
    const unsigned short* __restrict__ h1,
    const float* __restrict__ sum1, const float* __restrict__ sumsq1,
    const float* __restrict__ g1, const float* __restrict__ be1,
    const float* __restrict__ W2, const float* __restrict__ b2,
    float* __restrict__ h2, float* __restrict__ sum2, float* __restrict__ sumsq2)
{
    __shared__ unsigned short Xs[64 * 128];    // 16 KB
    __shared__ unsigned short Wsm[128 * 128];  // 32 KB
    __shared__ float a1s[256], c1s[256];

    const int tid = threadIdx.x;
    const int row0 = blockIdx.x * 64;

    {   // BN1 affine: hn = a*h + c
        float s = sum1[tid], q = sumsq1[tid];
        float mu = s * INV_B;
        float var = fmaf(q, INV_B, -mu * mu);
        float rs = rsqrtf(var + BN_EPS_C);
        float a = g1[tid] * rs;
        a1s[tid] = a;
        c1s[tid] = fmaf(-mu, a, be1[tid]);
    }
    __syncthreads();

    const int w = tid >> 6, lane = tid & 63;
    const int wm = w & 1, wn = w >> 1;
    const int lr = lane & 15, lk = lane >> 4;
    f32x4 acc[2][4];
#pragma unroll
    for (int i = 0; i < 2; ++i)
#pragma unroll
        for (int j = 0; j < 4; ++j) acc[i][j] = (f32x4){0.f, 0.f, 0.f, 0.f};

    for (int kt = 0; kt < 2; ++kt) {
        if (kt) __syncthreads();
        // stage X with BN affine (bf16 in, bf16 out)
#pragma unroll
        for (int iter = 0; iter < 4; ++iter) {
            int idx = iter * 256 + tid;
            int row = idx >> 4, chunk = idx & 15;
            int k0 = kt * 128 + chunk * 8;
            bf16x8 hv = *(const bf16x8*)(h1 + (size_t)(row0 + row) * 256 + k0);
            bf16x8 sv;
#pragma unroll
            for (int j = 0; j < 8; ++j) {
                float f = bf2f((unsigned short)hv[j]);
                f = fmaf(a1s[k0 + j], f, c1s[k0 + j]);
                sv[j] = (short)f2bf(f);
            }
            *(bf16x8*)((char*)Xs + swz(row, chunk * 16)) = sv;
        }
        // stage W2 K-half
#pragma unroll
        for (int iter = 0; iter < 8; ++iter) {
            int idx = iter * 256 + tid;
            int n = idx >> 4, chunk = idx & 15;
            const float* src = W2 + (size_t)n * 256 + kt * 128 + chunk * 8;
            float4 va = ((const float4*)src)[0];
            float4 vb = ((const float4*)src)[1];
            bf16x8 sv;
            sv[0] = (short)f2bf(va.x); sv[1] = (short)f2bf(va.y);
            sv[2] = (short)f2bf(va.z); sv[3] = (short)f2bf(va.w);
            sv[4] = (short)f2bf(vb.x); sv[5] = (short)f2bf(vb.y);
            sv[6] = (short)f2bf(vb.z); sv[7] = (short)f2bf(vb.w);
            *(bf16x8*)((char*)Wsm + swz(n, chunk * 16)) = sv;
        }
        __syncthreads();

#pragma unroll
        for (int kst = 0; kst < 4; ++kst) {
            int kbyte = kst * 64 + lk * 16;
            bf16x8 a[2], b[4];
#pragma unroll
            for (int mi = 0; mi < 2; ++mi)
                a[mi] = *(const bf16x8*)((const char*)Xs + swz(wm * 32 + mi * 16 + lr, kbyte));
#pragma unroll
            for (int nj = 0; nj < 4; ++nj)
                b[nj] = *(const bf16x8*)((const char*)Wsm + swz(wn * 64 + nj * 16 + lr, kbyte));
#pragma unroll
            for (int mi = 0; mi < 2; ++mi)
#pragma unroll
                for (int nj = 0; nj < 4; ++nj)
                    acc[mi][nj] = __builtin_amdgcn_mfma_f32_16x16x32_bf16(a[mi], b[nj], acc[mi][nj], 0, 0, 0);
        }
    }

    __syncthreads();
    float* ssum = (float*)Wsm;
    float* ssq  = ssum + 128;
    if (tid < 128) { ssum[tid] = 0.f; ssq[tid] = 0.f; }

    float bias[4];
#pragma unroll
    for (int nj = 0; nj < 4; ++nj) bias[nj] = b2[wn * 64 + nj * 16 + lr];

    float sums[4] = {0.f, 0.f, 0.f, 0.f}, sqs[4] = {0.f, 0.f, 0.f, 0.f};
#pragma unroll
    for (int mi = 0; mi < 2; ++mi)
#pragma unroll
        for (int nj = 0; nj < 4; ++nj)
#pragma unroll
            for (int reg = 0; reg < 4; ++reg) {
                int grow = row0 + wm * 32 + mi * 16 + lk * 4 + reg;
                int col = wn * 64 + nj * 16 + lr;
                float v = fmaxf(acc[mi][nj][reg] + bias[nj], 0.f);
                h2[(size_t)grow * 128 + col] = v;
                sums[nj] += v; sqs[nj] += v * v;
            }
    __syncthreads();
#pragma unroll
    for (int nj = 0; nj < 4; ++nj) {
        float s = sums[nj], q = sqs[nj];
        s += __shfl_xor(s, 16); s += __shfl_xor(s, 32);
        q += __shfl_xor(q, 16); q += __shfl_xor(q, 32);
        if (lane < 16) {
            atomicAdd(&ssum[wn * 64 + nj * 16 + lane], s);
            atomicAdd(&ssq[wn * 64 + nj * 16 + lane], q);
        }
    }
    __syncthreads();
    if (tid < 128) {
        atomicAdd(&sum2[tid], ssum[tid]);
        atomicAdd(&sumsq2[tid], ssq[tid]);
    }
}

// ---------------------------------------------------------------------------
// K3: BN2 folded into per-feature (a2*W3, c2*W3); deep dot (4 lanes/row),
//     + wide gather + biases, sigmoid -> out.  64 rows per block.
// ---------------------------------------------------------------------------
__global__ __launch_bounds__(256) void wd_k3(
    const int* __restrict__ ui, const int* __restrict__ ii,
    const float* __restrict__ wide_w, const float* __restrict__ wide_b,
    const float* __restrict__ h2,
    const float* __restrict__ sum2, const float* __restrict__ sumsq2,
    const float* __restrict__ g2, const float* __restrict__ be2,
    const float* __restrict__ W3, const float* __restrict__ b3,
    float* __restrict__ out)
{
    __shared__ float af[128], cf[128];
    const int tid = threadIdx.x;
    if (tid < 128) {
        float s = sum2[tid], q = sumsq2[tid];
        float mu = s * INV_B;
        float var = fmaf(q, INV_B, -mu * mu);
        float rs = rsqrtf(var + BN_EPS_C);
        float a = g2[tid] * rs;
        float c = fmaf(-mu, a, be2[tid]);
        float w = W3[tid];
        af[tid] = a * w;
        cf[tid] = c * w;
    }
    __syncthreads();

    const int row = blockIdx.x * 64 + (tid >> 2);
    const int kq = tid & 3;
    const float* hrow = h2 + (size_t)row * 128 + kq * 32;
    const float* afp = af + kq * 32;
    const float* cfp = cf + kq * 32;
    float acc = 0.f;
#pragma unroll
    for (int j = 0; j < 8; ++j) {
        float4 h = *(const float4*)&hrow[j * 4];
        float4 a4 = *(const float4*)&afp[j * 4];
        float4 c4 = *(const float4*)&cfp[j * 4];
        acc += fmaf(h.x, a4.x, c4.x);
        acc += fmaf(h.y, a4.y, c4.y);
        acc += fmaf(h.z, a4.z, c4.z);
        acc += fmaf(h.w, a4.w, c4.w);
    }
    acc += __shfl_xor(acc, 1);
    acc += __shfl_xor(acc, 2);
    if (kq == 0) {
        int u = ui[row], iv = ii[row];
        float wide = wide_w[u] + wide_w[NUM_USERS_C + iv] + wide_b[0];
        float logit = acc + b3[0] + wide;
        out[row] = 1.f / (1.f + expf(-logit));
    }
}

extern "C" void kernel_launch(void* const* d_in, const int* in_sizes, int n_in,
                              void* d_out, int out_size, void* d_ws, size_t ws_size,
                              hipStream_t stream)
{
    const int*   ui     = (const int*)d_in[0];
    const int*   ii     = (const int*)d_in[1];
    const float* wide_w = (const float*)d_in[2];
    const float* wide_b = (const float*)d_in[3];
    const float* utab   = (const float*)d_in[4];
    const float* itab   = (const float*)d_in[5];
    const float* W1     = (const float*)d_in[6];
    const float* b1     = (const float*)d_in[7];
    const float* g1     = (const float*)d_in[8];
    const float* be1    = (const float*)d_in[9];
    const float* W2     = (const float*)d_in[10];
    const float* b2     = (const float*)d_in[11];
    const float* g2     = (const float*)d_in[12];
    const float* be2    = (const float*)d_in[13];
    const float* W3     = (const float*)d_in[14];
    const float* b3     = (const float*)d_in[15];
    float* out = (float*)d_out;

    char* base = (char*)d_ws;
    unsigned short* h1 = (unsigned short*)base;                            // 16384*256 bf16
    float* h2 = (float*)(base + (size_t)16384 * 256 * 2);                  // 16384*128 f32
    float* stats = (float*)(base + (size_t)16384 * 256 * 2 + (size_t)16384 * 128 * 4);
    float* sum1 = stats;
    float* sumsq1 = stats + 256;
    float* sum2 = stats + 512;
    float* sumsq2 = stats + 640;

    hipMemsetAsync(stats, 0, 768 * sizeof(float), stream);

    wd_k1<<<dim3(2, 128), 256, 0, stream>>>(ui, ii, utab, itab, W1, b1, h1, sum1, sumsq1);
    wd_k2<<<256, 256, 0, stream>>>(h1, sum1, sumsq1, g1, be1, W2, b2, h2, sum2, sumsq2);
    wd_k3<<<256, 256, 0, stream>>>(ui, ii, wide_w, wide_b, h2, sum2, sumsq2, g2, be2, W3, b3, out);
}